// Round 3
// baseline (3886.764 us; speedup 1.0000x reference)
//
#include <hip/hip_runtime.h>
#include <cstdint>
#include <cstddef>

#define B_ 64
#define T_ 512
#define I_ 256
#define H_ 1024
#define O_ 128

typedef __attribute__((ext_vector_type(8))) short short8;   // 8 x bf16 frag
typedef __attribute__((ext_vector_type(4))) float f32x4;    // MFMA accumulator

__device__ __forceinline__ unsigned short f2bf(float f) {
    union { float f; unsigned int u; } v; v.f = f;
    unsigned int r = v.u + 0x7fffu + ((v.u >> 16) & 1u);   // RNE
    return (unsigned short)(r >> 16);
}
__device__ __forceinline__ float bf2f(unsigned short h) {
    union { float f; unsigned int u; } v; v.u = ((unsigned int)h) << 16;
    return v.f;
}
__device__ __forceinline__ short8 pack8(const float* p) {
    float4 a = *(const float4*)p;
    float4 b = *(const float4*)(p + 4);
    short8 r;
    r[0] = (short)f2bf(a.x); r[1] = (short)f2bf(a.y);
    r[2] = (short)f2bf(a.z); r[3] = (short)f2bf(a.w);
    r[4] = (short)f2bf(b.x); r[5] = (short)f2bf(b.y);
    r[6] = (short)f2bf(b.z); r[7] = (short)f2bf(b.w);
    return r;
}
__device__ __forceinline__ f32x4 zero4() {
    f32x4 v; v[0] = 0.f; v[1] = 0.f; v[2] = 0.f; v[3] = 0.f; return v;
}

// ---------------------------------------------------------------------------
// Phase A: xp[t][b][h] = x[b][t][:] . W_ih[h][:] + b_ih[h] + b_hh[h]
// Grid (16 ntile, 64 tgroup). Each WG does 8 consecutive timesteps with its
// W_ih fragments (64 VGPR/lane) + biases register-resident. x[t] staged per
// step: one wave loads one 1 KB row contiguously (perfect coalescing).
// ---------------------------------------------------------------------------
#define XS 264   // LDS row stride (shorts): 528 B, 16B-aligned

__global__ __launch_bounds__(256) void xproj_kernel(
        const float* __restrict__ x, const float* __restrict__ W_ih,
        const float* __restrict__ b_ih, const float* __restrict__ b_hh,
        unsigned short* __restrict__ xp) {
    const int ntile = blockIdx.x;        // 0..15
    const int tg    = blockIdx.y;        // 0..63 (8 t's each)
    const int tid   = threadIdx.x;
    const int wave  = tid >> 6, lane = tid & 63;
    const int m     = lane & 15, quad = lane >> 4;
    const int wrow  = (wave & 1) * 32;
    const int wcol  = (wave >> 1) * 32;

    __shared__ unsigned short lds_x[64 * XS];

    // register-resident W_ih B-frags + biases for this WG's 64 columns
    short8 bfr[2][8];
    float  bias[2];
    #pragma unroll
    for (int ct = 0; ct < 2; ++ct) {
        const int col = ntile * 64 + wcol + ct * 16 + m;
        bias[ct] = b_ih[col] + b_hh[col];
        #pragma unroll
        for (int ks = 0; ks < 8; ++ks)
            bfr[ct][ks] = pack8(W_ih + (size_t)col * I_ + ks * 32 + quad * 8);
    }

    for (int it = 0; it < 8; ++it) {
        const int t = tg * 8 + it;

        // stage x[:, t, :] -> bf16 LDS; wave w covers row j*4+w (1 KB contig)
        #pragma unroll
        for (int j = 0; j < 16; ++j) {
            const int row = j * 4 + wave;
            float4 v = *(const float4*)(x + ((size_t)row * T_ + t) * I_ + lane * 4);
            uint2 p;
            p.x = (unsigned)f2bf(v.x) | ((unsigned)f2bf(v.y) << 16);
            p.y = (unsigned)f2bf(v.z) | ((unsigned)f2bf(v.w) << 16);
            *(uint2*)(&lds_x[row * XS + lane * 4]) = p;
        }
        __syncthreads();

        f32x4 acc[2][2];
        #pragma unroll
        for (int i = 0; i < 2; ++i)
            #pragma unroll
            for (int j = 0; j < 2; ++j) acc[i][j] = zero4();

        #pragma unroll
        for (int ks = 0; ks < 8; ++ks) {
            const int kb = ks * 32 + quad * 8;
            short8 af[2];
            #pragma unroll
            for (int rt = 0; rt < 2; ++rt)
                af[rt] = *(const short8*)(&lds_x[(wrow + rt * 16 + m) * XS + kb]);
            #pragma unroll
            for (int rt = 0; rt < 2; ++rt)
                #pragma unroll
                for (int ct = 0; ct < 2; ++ct)
                    acc[rt][ct] = __builtin_amdgcn_mfma_f32_16x16x32_bf16(
                        af[rt], bfr[ct][ks], acc[rt][ct], 0, 0, 0);
        }

        // C/D layout: col=lane&15, row=quad*4+reg
        #pragma unroll
        for (int ct = 0; ct < 2; ++ct) {
            const int col = ntile * 64 + wcol + ct * 16 + m;
            #pragma unroll
            for (int rt = 0; rt < 2; ++rt)
                #pragma unroll
                for (int r = 0; r < 4; ++r) {
                    const int bl = wrow + rt * 16 + quad * 4 + r;
                    xp[((size_t)t * B_ + bl) * H_ + col] =
                        f2bf(acc[rt][ct][r] + bias[ct]);
                }
        }
        __syncthreads();   // lds_x safe to restage next t
    }
}

// ---------------------------------------------------------------------------
// Phase B: persistent recurrence. 64 WGs = 4 batch-groups x 16 col-slices.
// W_hh slice register-resident (128 VGPR/lane). h exchanged through IF$ via
// agent-scope RELAXED atomic 8B loads/stores (sc0/sc1: bypass L1/L2, always
// coherent) -> the barrier needs NO wbl2 / NO buffer_inv / NO fences:
//   stores -> __syncthreads (vmcnt drain per wave) -> relaxed fetch_add ->
//   relaxed spin -> __syncthreads.
// ---------------------------------------------------------------------------
#define LDS_STRIDE 1032   // 1024 + 8 bf16 pad; rows 16B-aligned
#define OUT_S 68          // 64 + 4 pad (shorts); rows 8B-aligned

__global__ __launch_bounds__(256, 1) void rnn_kernel(
        const float* __restrict__ W_hh, const unsigned short* __restrict__ xp,
        unsigned short* __restrict__ hbuf, unsigned int* __restrict__ barrier_ctr) {
    const int group = blockIdx.x >> 4;   // 0..3  (16 batch rows each)
    const int slice = blockIdx.x & 15;   // 0..15 (64 H-cols each)
    const int tid   = threadIdx.x;
    const int wave  = tid >> 6, lane = tid & 63;
    const int m     = lane & 15, quad = lane >> 4;
    const int col   = slice * 64 + wave * 16 + m;   // this lane's B column

    __shared__ unsigned short lds_h[16 * LDS_STRIDE];
    __shared__ unsigned short lds_out[16 * OUT_S];

    // Preload W_hh B-frags: bfrag[ks] = W_hh[col][ks*32 + quad*8 ..]
    short8 bfrag[32];
    #pragma unroll
    for (int ks = 0; ks < 32; ++ks)
        bfrag[ks] = pack8(W_hh + (size_t)col * H_ + ks * 32 + quad * 8);

    unsigned int* ctr = barrier_ctr + group * 32;   // 128B-separated counters
    const int srow = tid & 15, sseg = tid >> 4;     // staging: (row, 8B-seg)
    const int orow = tid >> 4, oseg = tid & 15;     // out: (row, 8B-seg)

    for (int t = 0; t < T_; ++t) {
        const unsigned short* hsrc = hbuf + (size_t)(t & 1) * (B_ * H_)
                                          + (size_t)group * 16 * H_;
        unsigned short* hdst = hbuf + (size_t)((t + 1) & 1) * (B_ * H_);

        // prefetch xp (normal cached loads; L1/L2 never invalidated now)
        unsigned short xpv[4];
        {
            const unsigned short* xpp =
                xp + ((size_t)t * B_ + group * 16 + quad * 4) * H_ + col;
            #pragma unroll
            for (int r = 0; r < 4; ++r) xpv[r] = xpp[(size_t)r * H_];
        }

        // stage 16x1024 bf16 (32 KB) via coherent 8B loads (IF$-direct)
        {
            unsigned long long* src8 =
                (unsigned long long*)(hsrc + (size_t)srow * H_);
            #pragma unroll
            for (int itr = 0; itr < 16; ++itr) {
                const int u = sseg + itr * 16;      // 8B unit within row
                unsigned long long v = __hip_atomic_load(
                    src8 + u, __ATOMIC_RELAXED, __HIP_MEMORY_SCOPE_AGENT);
                *(unsigned long long*)(&lds_h[srow * LDS_STRIDE + u * 4]) = v;
            }
        }
        __syncthreads();

        // K loop: 4 independent accumulator chains
        f32x4 acc[4];
        #pragma unroll
        for (int j = 0; j < 4; ++j) acc[j] = zero4();
        #pragma unroll
        for (int ks = 0; ks < 32; ks += 4) {
            #pragma unroll
            for (int j = 0; j < 4; ++j) {
                short8 a = *(const short8*)(
                    &lds_h[m * LDS_STRIDE + (ks + j) * 32 + quad * 8]);
                acc[j] = __builtin_amdgcn_mfma_f32_16x16x32_bf16(
                    a, bfrag[ks + j], acc[j], 0, 0, 0);
            }
        }

        // epilogue: +xp, tanh -> LDS transpose buffer
        #pragma unroll
        for (int r = 0; r < 4; ++r) {
            float v = acc[0][r] + acc[1][r] + acc[2][r] + acc[3][r]
                    + bf2f(xpv[r]);
            v = tanhf(v);
            lds_out[(quad * 4 + r) * OUT_S + wave * 16 + m] = f2bf(v);
        }
        __syncthreads();

        // publish own 16x64 slice: one coherent 8B store per thread
        {
            unsigned long long v =
                *(const unsigned long long*)(&lds_out[orow * OUT_S + oseg * 4]);
            __hip_atomic_store(
                (unsigned long long*)(hdst + ((size_t)(group * 16 + orow)) * H_
                                      + slice * 64 + oseg * 4),
                v, __ATOMIC_RELAXED, __HIP_MEMORY_SCOPE_AGENT);
        }

        if (t < T_ - 1) {
            __syncthreads();   // every wave: s_waitcnt vmcnt(0) before barrier
                               // -> all WG stores are at IF$ when tid0 runs
            if (tid == 0) {
                __hip_atomic_fetch_add(ctr, 1u, __ATOMIC_RELAXED,
                                       __HIP_MEMORY_SCOPE_AGENT);
                const unsigned int target = 16u * (unsigned int)(t + 1);
                while (__hip_atomic_load(ctr, __ATOMIC_RELAXED,
                                         __HIP_MEMORY_SCOPE_AGENT) < target) {}
            }
            __syncthreads();
        }
    }
}

// ---------------------------------------------------------------------------
// Phase C: out[b][o] = h_final[b][:] . W_lin[o][:] + b_lin[o]; one wave/output
// ---------------------------------------------------------------------------
__global__ __launch_bounds__(256) void out_kernel(
        const unsigned short* __restrict__ hfinal, const float* __restrict__ W_lin,
        const float* __restrict__ b_lin, float* __restrict__ out) {
    const int gwave = (int)((blockIdx.x * 256 + threadIdx.x) >> 6);  // 0..8191
    const int lane  = threadIdx.x & 63;
    const int b = gwave >> 7, o = gwave & 127;

    const unsigned short* hp = hfinal + (size_t)b * H_ + lane * 16;
    const float*          wp = W_lin  + (size_t)o * H_ + lane * 16;
    float s = 0.f;
    #pragma unroll
    for (int j = 0; j < 16; ++j) s += bf2f(hp[j]) * wp[j];
    #pragma unroll
    for (int d = 32; d > 0; d >>= 1) s += __shfl_down(s, d, 64);
    if (lane == 0) out[(size_t)b * O_ + o] = s + b_lin[o];
}

// ---------------------------------------------------------------------------
extern "C" void kernel_launch(void* const* d_in, const int* in_sizes, int n_in,
                              void* d_out, int out_size, void* d_ws, size_t ws_size,
                              hipStream_t stream) {
    const float* x     = (const float*)d_in[0];
    const float* W_ih  = (const float*)d_in[1];
    const float* W_hh  = (const float*)d_in[2];
    const float* b_ih  = (const float*)d_in[3];
    const float* b_hh  = (const float*)d_in[4];
    const float* W_lin = (const float*)d_in[5];
    const float* b_lin = (const float*)d_in[6];

    const size_t XP_ELEMS = (size_t)T_ * B_ * H_;        // 33.5M bf16 = 64 MB
    unsigned short* xp   = (unsigned short*)d_ws;
    unsigned short* hbuf = xp + XP_ELEMS;                // 2 x (64*1024) bf16
    unsigned int*   ctr  = (unsigned int*)(hbuf + 2 * (size_t)B_ * H_);

    // zero h0 (+h1) and barrier counters (ws is re-poisoned 0xAA every launch)
    hipMemsetAsync(hbuf, 0,
                   2 * (size_t)B_ * H_ * sizeof(unsigned short)
                   + 4 * 32 * sizeof(unsigned int), stream);

    dim3 gA(H_ / 64, T_ / 8);   // (ntile, tgroup)
    xproj_kernel<<<gA, 256, 0, stream>>>(x, W_ih, b_ih, b_hh, xp);
    rnn_kernel<<<64, 256, 0, stream>>>(W_hh, xp, hbuf, ctr);
    out_kernel<<<(B_ * O_) / 4, 256, 0, stream>>>(hbuf, W_lin, b_lin, (float*)d_out);
}

// Round 5
// 2014.598 us; speedup vs baseline: 1.9293x; 1.9293x over previous
//
#include <hip/hip_runtime.h>
#include <cstdint>
#include <cstddef>

#define B_ 64
#define T_ 512
#define I_ 256
#define H_ 1024
#define O_ 128

typedef __attribute__((ext_vector_type(8))) short short8;   // 8 x bf16 frag
typedef __attribute__((ext_vector_type(4))) float f32x4;    // MFMA accumulator

__device__ __forceinline__ unsigned short f2bf(float f) {
    union { float f; unsigned int u; } v; v.f = f;
    unsigned int r = v.u + 0x7fffu + ((v.u >> 16) & 1u);   // RNE
    return (unsigned short)(r >> 16);
}
__device__ __forceinline__ float bf2f(unsigned short h) {
    union { float f; unsigned int u; } v; v.u = ((unsigned int)h) << 16;
    return v.f;
}
__device__ __forceinline__ short8 pack8(const float* p) {
    float4 a = *(const float4*)p;
    float4 b = *(const float4*)(p + 4);
    short8 r;
    r[0] = (short)f2bf(a.x); r[1] = (short)f2bf(a.y);
    r[2] = (short)f2bf(a.z); r[3] = (short)f2bf(a.w);
    r[4] = (short)f2bf(b.x); r[5] = (short)f2bf(b.y);
    r[6] = (short)f2bf(b.z); r[7] = (short)f2bf(b.w);
    return r;
}
__device__ __forceinline__ f32x4 zero4() {
    f32x4 v; v[0] = 0.f; v[1] = 0.f; v[2] = 0.f; v[3] = 0.f; return v;
}

// ---------------------------------------------------------------------------
// Phase A: xp[t][b][h] = x[b][t][:] . W_ih[h][:] + b_ih[h] + b_hh[h]
// (unchanged; validated rounds 3-4 structure)
// ---------------------------------------------------------------------------
#define XS 264   // LDS row stride (shorts)

__global__ __launch_bounds__(256) void xproj_kernel(
        const float* __restrict__ x, const float* __restrict__ W_ih,
        const float* __restrict__ b_ih, const float* __restrict__ b_hh,
        unsigned short* __restrict__ xp) {
    const int ntile = blockIdx.x;        // 0..15
    const int tg    = blockIdx.y;        // 0..63 (8 t's each)
    const int tid   = threadIdx.x;
    const int wave  = tid >> 6, lane = tid & 63;
    const int m     = lane & 15, quad = lane >> 4;
    const int wrow  = (wave & 1) * 32;
    const int wcol  = (wave >> 1) * 32;

    __shared__ unsigned short lds_x[64 * XS];

    short8 bfr[2][8];
    float  bias[2];
    #pragma unroll
    for (int ct = 0; ct < 2; ++ct) {
        const int col = ntile * 64 + wcol + ct * 16 + m;
        bias[ct] = b_ih[col] + b_hh[col];
        #pragma unroll
        for (int ks = 0; ks < 8; ++ks)
            bfr[ct][ks] = pack8(W_ih + (size_t)col * I_ + ks * 32 + quad * 8);
    }

    for (int it = 0; it < 8; ++it) {
        const int t = tg * 8 + it;
        #pragma unroll
        for (int j = 0; j < 16; ++j) {
            const int row = j * 4 + wave;
            float4 v = *(const float4*)(x + ((size_t)row * T_ + t) * I_ + lane * 4);
            uint2 p;
            p.x = (unsigned)f2bf(v.x) | ((unsigned)f2bf(v.y) << 16);
            p.y = (unsigned)f2bf(v.z) | ((unsigned)f2bf(v.w) << 16);
            *(uint2*)(&lds_x[row * XS + lane * 4]) = p;
        }
        __syncthreads();

        f32x4 acc[2][2];
        #pragma unroll
        for (int i = 0; i < 2; ++i)
            #pragma unroll
            for (int j = 0; j < 2; ++j) acc[i][j] = zero4();

        #pragma unroll
        for (int ks = 0; ks < 8; ++ks) {
            const int kb = ks * 32 + quad * 8;
            short8 af[2];
            #pragma unroll
            for (int rt = 0; rt < 2; ++rt)
                af[rt] = *(const short8*)(&lds_x[(wrow + rt * 16 + m) * XS + kb]);
            #pragma unroll
            for (int rt = 0; rt < 2; ++rt)
                #pragma unroll
                for (int ct = 0; ct < 2; ++ct)
                    acc[rt][ct] = __builtin_amdgcn_mfma_f32_16x16x32_bf16(
                        af[rt], bfr[ct][ks], acc[rt][ct], 0, 0, 0);
        }

        #pragma unroll
        for (int ct = 0; ct < 2; ++ct) {
            const int col = ntile * 64 + wcol + ct * 16 + m;
            #pragma unroll
            for (int rt = 0; rt < 2; ++rt)
                #pragma unroll
                for (int r = 0; r < 4; ++r) {
                    const int bl = wrow + rt * 16 + quad * 4 + r;
                    xp[((size_t)t * B_ + bl) * H_ + col] =
                        f2bf(acc[rt][ct][r] + bias[ct]);
                }
        }
        __syncthreads();
    }
}

// ---------------------------------------------------------------------------
// Phase B: persistent recurrence, dataflow-synced.
// 64 WGs = 4 groups (16 batch rows) x 16 col-slices (64 cols). W_hh slice
// register-resident. ALL h exchange + flags via plain `sc0 sc1` global ops
// (coherent at IF$ — round-3-validated semantics, full-width coalesced).
// Per-wave flags: producer wave publishes its 16-col chunk, drains vmcnt,
// lane0 stores flag=t+1. Consumers poll all 64 group flags in ONE vector
// load + ballot. No central barrier, no RMW polling, no wbl2/inv ever.
// 2-buffer ping-pong safe: passing the poll at step t implies every WG
// finished consuming h_{t-1}.
// ---------------------------------------------------------------------------
#define LDS_STRIDE 1032   // 1024 + 8 bf16 pad; rows 16B-aligned
#define PO_S 20           // per-wave out tile stride (shorts): 40B, 8B-aligned

__global__ __launch_bounds__(256, 1) void rnn_kernel(
        const float* __restrict__ W_hh, const unsigned short* __restrict__ xp,
        unsigned short* __restrict__ hbuf, unsigned int* __restrict__ flags) {
    const int group = blockIdx.x >> 4;   // 0..3  (16 batch rows each)
    const int slice = blockIdx.x & 15;   // 0..15 (64 H-cols each)
    const int tid   = threadIdx.x;
    const int wave  = tid >> 6, lane = tid & 63;
    const int m     = lane & 15, quad = lane >> 4;
    const int col   = slice * 64 + wave * 16 + m;   // this lane's B column

    __shared__ unsigned short lds_h[16 * LDS_STRIDE];
    __shared__ unsigned short lds_po[4][16 * PO_S];

    // Preload W_hh B-frags: bfrag[ks] = W_hh[col][ks*32 + quad*8 ..]
    short8 bfrag[32];
    #pragma unroll
    for (int ks = 0; ks < 32; ++ks)
        bfrag[ks] = pack8(W_hh + (size_t)col * H_ + ks * 32 + quad * 8);

    unsigned int* gflags = flags + group * 64;          // 64 wave-flags, 256 B
    unsigned int* myflag = gflags + slice * 4 + wave;
    const unsigned int* pollp = gflags + lane;          // lane i polls flag i

    const int srow = tid >> 4, useg = tid & 15;         // staging role
    const int prow = lane >> 2, pseg = lane & 3;        // publish role

    for (int t = 0; t < T_; ++t) {
        const unsigned short* hsrc = hbuf + (size_t)(t & 1) * (B_ * H_)
                                          + (size_t)group * 16 * H_;
        unsigned short* hdst = hbuf + (size_t)((t + 1) & 1) * (B_ * H_);

        // xp prefetch (plain cached loads; caches never invalidated)
        unsigned short xpv[4];
        {
            const unsigned short* xpp =
                xp + ((size_t)t * B_ + group * 16 + quad * 4) * H_ + col;
            #pragma unroll
            for (int r = 0; r < 4; ++r) xpv[r] = xpp[(size_t)r * H_];
        }

        // poll: wait until all 64 producer-wave flags of this group >= t
        if (t > 0) {
            const unsigned int target = (unsigned int)t;
            while (true) {
                unsigned int fv;
                asm volatile(
                    "global_load_dword %0, %1, off sc0 sc1\n\t"
                    "s_waitcnt vmcnt(0)"
                    : "=v"(fv) : "v"(pollp) : "memory");
                if (__ballot(fv >= target) == ~0ull) break;
            }
        }

        // cooperative stage: 16 x 1024 bf16 (32 KB) via sc0 sc1 dwordx4
        {
            const unsigned short* rp = hsrc + (size_t)srow * H_;
            uint4 sv[8];
            #pragma unroll
            for (int k = 0; k < 8; ++k) {
                const void* p = rp + (useg + 16 * k) * 8;
                asm volatile("global_load_dwordx4 %0, %1, off sc0 sc1"
                             : "=v"(sv[k]) : "v"(p) : "memory");
            }
            asm volatile("s_waitcnt vmcnt(0)" ::: "memory");
            #pragma unroll
            for (int k = 0; k < 8; ++k)
                *(uint4*)(&lds_h[srow * LDS_STRIDE + (useg + 16 * k) * 8]) = sv[k];
        }
        __syncthreads();   // S_b: staged data visible to all waves

        // K loop: 4 independent accumulator chains
        f32x4 acc[4];
        #pragma unroll
        for (int j = 0; j < 4; ++j) acc[j] = zero4();
        #pragma unroll
        for (int ks = 0; ks < 32; ks += 4) {
            #pragma unroll
            for (int j = 0; j < 4; ++j) {
                short8 a = *(const short8*)(
                    &lds_h[m * LDS_STRIDE + (ks + j) * 32 + quad * 8]);
                acc[j] = __builtin_amdgcn_mfma_f32_16x16x32_bf16(
                    a, bfrag[ks + j], acc[j], 0, 0, 0);
            }
        }

        // epilogue: +xp, tanh -> per-wave LDS transpose tile (16 rows x 16 cols)
        #pragma unroll
        for (int r = 0; r < 4; ++r) {
            float v = acc[0][r] + acc[1][r] + acc[2][r] + acc[3][r]
                    + bf2f(xpv[r]);
            v = tanhf(v);
            lds_po[wave][(quad * 4 + r) * PO_S + m] = f2bf(v);
        }
        // wave-local readback (compiler inserts lgkmcnt) + coherent publish
        {
            unsigned long long v = *(const unsigned long long*)(
                &lds_po[wave][prow * PO_S + pseg * 4]);
            const void* p = hdst + (size_t)(group * 16 + prow) * H_
                            + slice * 64 + wave * 16 + pseg * 4;
            asm volatile("global_store_dwordx2 %0, %1, off sc0 sc1"
                         :: "v"(p), "v"(v) : "memory");
            asm volatile("s_waitcnt vmcnt(0)" ::: "memory");
        }
        // publish flag (wave-local: own chunk is fully at IF$)
        if (lane == 0 && t < T_ - 1) {
            unsigned int fv = (unsigned int)(t + 1);
            asm volatile("global_store_dword %0, %1, off sc0 sc1"
                         :: "v"(myflag), "v"(fv) : "memory");
        }
        __syncthreads();   // S_a: all waves done reading lds_h before restage
    }
}

// ---------------------------------------------------------------------------
// Phase C: out[b][o] = h_final[b][:] . W_lin[o][:] + b_lin[o]; one wave/output
// ---------------------------------------------------------------------------
__global__ __launch_bounds__(256) void out_kernel(
        const unsigned short* __restrict__ hfinal, const float* __restrict__ W_lin,
        const float* __restrict__ b_lin, float* __restrict__ out) {
    const int gwave = (int)((blockIdx.x * 256 + threadIdx.x) >> 6);  // 0..8191
    const int lane  = threadIdx.x & 63;
    const int b = gwave >> 7, o = gwave & 127;

    const unsigned short* hp = hfinal + (size_t)b * H_ + lane * 16;
    const float*          wp = W_lin  + (size_t)o * H_ + lane * 16;
    float s = 0.f;
    #pragma unroll
    for (int j = 0; j < 16; ++j) s += bf2f(hp[j]) * wp[j];
    #pragma unroll
    for (int d = 32; d > 0; d >>= 1) s += __shfl_down(s, d, 64);
    if (lane == 0) out[(size_t)b * O_ + o] = s + b_lin[o];
}

// ---------------------------------------------------------------------------
extern "C" void kernel_launch(void* const* d_in, const int* in_sizes, int n_in,
                              void* d_out, int out_size, void* d_ws, size_t ws_size,
                              hipStream_t stream) {
    const float* x     = (const float*)d_in[0];
    const float* W_ih  = (const float*)d_in[1];
    const float* W_hh  = (const float*)d_in[2];
    const float* b_ih  = (const float*)d_in[3];
    const float* b_hh  = (const float*)d_in[4];
    const float* W_lin = (const float*)d_in[5];
    const float* b_lin = (const float*)d_in[6];

    const size_t XP_ELEMS = (size_t)T_ * B_ * H_;        // 33.5M bf16 = 64 MB
    unsigned short* xp    = (unsigned short*)d_ws;
    unsigned short* hbuf  = xp + XP_ELEMS;               // 2 x (64*1024) bf16
    unsigned int*   flags = (unsigned int*)(hbuf + 2 * (size_t)B_ * H_);

    // zero h ping-pong + flags (ws re-poisoned 0xAA before every launch)
    hipMemsetAsync(hbuf, 0,
                   2 * (size_t)B_ * H_ * sizeof(unsigned short)
                   + 4 * 64 * sizeof(unsigned int), stream);

    dim3 gA(H_ / 64, T_ / 8);   // (ntile, tgroup)
    xproj_kernel<<<gA, 256, 0, stream>>>(x, W_ih, b_ih, b_hh, xp);
    rnn_kernel<<<64, 256, 0, stream>>>(W_hh, xp, hbuf, flags);
    out_kernel<<<(B_ * O_) / 4, 256, 0, stream>>>(hbuf, W_lin, b_lin, (float*)d_out);
}